// Round 1
// baseline (353.333 us; speedup 1.0000x reference)
//
#include <hip/hip_runtime.h>

// SimpleSelfAttention: B=4, S=2048, D=1024, fp32 in/out, bf16 MFMA internally.
// Pipeline: cvt(x,w) -> 3x QKV gemm_bt -> transpose V -> scores gemm(+mask,/32)
//           -> row softmax (in place, bf16 P) -> PV gemm -> fp32 out.

typedef __attribute__((ext_vector_type(8))) short short8;
typedef __attribute__((ext_vector_type(4))) short short4v;
typedef __attribute__((ext_vector_type(4))) float float4v;

__device__ __forceinline__ short f2bf(float f) {
  unsigned u = __builtin_bit_cast(unsigned, f);
  u += 0x7fffu + ((u >> 16) & 1u);           // RNE; inputs finite
  return (short)(u >> 16);
}
__device__ __forceinline__ float bf2f(short s) {
  unsigned u = ((unsigned)(unsigned short)s) << 16;
  return __builtin_bit_cast(float, u);
}

// ---------- fp32 -> bf16 cast, n4 = n/4 ----------
__global__ __launch_bounds__(256) void cvt_kernel(const float* __restrict__ in,
                                                  short* __restrict__ out, int n4) {
  int i = blockIdx.x * 256 + threadIdx.x;
  if (i < n4) {
    float4v v = ((const float4v*)in)[i];
    short4v o;
    o.x = f2bf(v.x); o.y = f2bf(v.y); o.z = f2bf(v.z); o.w = f2bf(v.w);
    ((short4v*)out)[i] = o;
  }
}

// ---------- C[m,n] = sum_k A[m,k]*B[n,k] (both K-contiguous), 128x128 tile ----------
// EPI 0: +bias[n], store bf16.  EPI 1: *scale + mask[m*N+n], store bf16.  EPI 2: store fp32.
template <int EPI>
__global__ __launch_bounds__(256) void gemm_bt(const short* __restrict__ Aall,
                                               const short* __restrict__ Ball,
                                               void* __restrict__ Call,
                                               const float* __restrict__ aux, float scale,
                                               int M, int N, int Kd,
                                               long ab, long bb, long cb) {
  const int bz = blockIdx.z;
  const short* A = Aall + (long)bz * ab;
  const short* Bm = Ball + (long)bz * bb;

  const int m0 = blockIdx.x * 128;
  const int n0 = blockIdx.y * 128;

  __shared__ alignas(16) short As[128][32];
  __shared__ alignas(16) short Bs[128][32];

  const int t = threadIdx.x;
  const int lane = t & 63, wave = t >> 6;
  const int wm = (wave & 1) * 64, wn = (wave >> 1) * 64;  // wave -> 64x64 subtile
  const int col = lane & 15, quad = lane >> 4;

  float4v acc[4][4] = {};

  for (int kt = 0; kt < Kd; kt += 32) {
    // stage 128x32 bf16 tiles: 512 chunks of 16B each per tile, 2 per thread
#pragma unroll
    for (int u = 0; u < 2; ++u) {
      int c = u * 256 + t;
      int row = c >> 2, c8 = (c & 3) << 3;
      *(short8*)&As[row][c8] = *(const short8*)&A[(long)(m0 + row) * Kd + kt + c8];
      *(short8*)&Bs[row][c8] = *(const short8*)&Bm[(long)(n0 + row) * Kd + kt + c8];
    }
    __syncthreads();

    short8 af[4], bfr[4];
#pragma unroll
    for (int i = 0; i < 4; ++i) af[i] = *(const short8*)&As[wm + i * 16 + col][quad * 8];
#pragma unroll
    for (int j = 0; j < 4; ++j) bfr[j] = *(const short8*)&Bs[wn + j * 16 + col][quad * 8];
#pragma unroll
    for (int i = 0; i < 4; ++i)
#pragma unroll
      for (int j = 0; j < 4; ++j)
        acc[i][j] = __builtin_amdgcn_mfma_f32_16x16x32_bf16(af[i], bfr[j], acc[i][j], 0, 0, 0);
    __syncthreads();
  }

  // C/D layout: col = lane&15, row = quad*4 + reg  (m89-verified)
#pragma unroll
  for (int i = 0; i < 4; ++i) {
#pragma unroll
    for (int j = 0; j < 4; ++j) {
      const int n = n0 + wn + j * 16 + col;
      float addv = 0.f;
      if (EPI == 0) addv = aux[n];
#pragma unroll
      for (int r = 0; r < 4; ++r) {
        const int m = m0 + wm + i * 16 + quad * 4 + r;
        float v = acc[i][j][r];
        if (EPI == 0) {
          ((short*)Call)[(long)bz * cb + (long)m * N + n] = f2bf(v + addv);
        } else if (EPI == 1) {
          v = v * scale + aux[(long)m * N + n];
          ((short*)Call)[(long)bz * cb + (long)m * N + n] = f2bf(v);
        } else {
          ((float*)Call)[(long)bz * cb + (long)m * N + n] = v;
        }
      }
    }
  }
}

// ---------- V[b][s][d] -> Vt[b][d][s], 32x32 tiles ----------
__global__ __launch_bounds__(256) void transpose_v(const short* __restrict__ V,
                                                   short* __restrict__ Vt) {
  __shared__ short tile[32][33];
  const int b = blockIdx.z;
  const int s0 = blockIdx.x * 32, d0 = blockIdx.y * 32;
  const int tx = threadIdx.x & 31, ty = threadIdx.x >> 5;
  const short* src = V + (long)b * 2048 * 1024;
#pragma unroll
  for (int q = 0; q < 4; ++q) {
    int r = ty + q * 8;
    tile[r][tx] = src[(long)(s0 + r) * 1024 + d0 + tx];
  }
  __syncthreads();
  short* dst = Vt + (long)b * 1024 * 2048;
#pragma unroll
  for (int q = 0; q < 4; ++q) {
    int dr = ty + q * 8;
    dst[(long)(d0 + dr) * 2048 + s0 + tx] = tile[tx][dr];
  }
}

// ---------- softmax over rows of 2048 bf16, in place ----------
__global__ __launch_bounds__(256) void softmax_kernel(short* __restrict__ Sb) {
  const long row = blockIdx.x;
  short* p = Sb + row * 2048;
  const int t = threadIdx.x;
  short8 raw = *(short8*)(p + t * 8);
  float v[8];
#pragma unroll
  for (int e = 0; e < 8; ++e) v[e] = bf2f(raw[e]);

  float mx = v[0];
#pragma unroll
  for (int e = 1; e < 8; ++e) mx = fmaxf(mx, v[e]);
#pragma unroll
  for (int off = 32; off > 0; off >>= 1) mx = fmaxf(mx, __shfl_xor(mx, off));
  __shared__ float redm[4], reds[4];
  if ((t & 63) == 0) redm[t >> 6] = mx;
  __syncthreads();
  mx = fmaxf(fmaxf(redm[0], redm[1]), fmaxf(redm[2], redm[3]));

  float s = 0.f, ev[8];
#pragma unroll
  for (int e = 0; e < 8; ++e) {
    ev[e] = exp2f((v[e] - mx) * 1.4426950408889634f);
    s += ev[e];
  }
#pragma unroll
  for (int off = 32; off > 0; off >>= 1) s += __shfl_xor(s, off);
  if ((t & 63) == 0) reds[t >> 6] = s;
  __syncthreads();
  s = reds[0] + reds[1] + reds[2] + reds[3];
  const float inv = 1.f / s;

  short8 outp;
#pragma unroll
  for (int e = 0; e < 8; ++e) outp[e] = f2bf(ev[e] * inv);
  *(short8*)(p + t * 8) = outp;
}

extern "C" void kernel_launch(void* const* d_in, const int* in_sizes, int n_in,
                              void* d_out, int out_size, void* d_ws, size_t ws_size,
                              hipStream_t stream) {
  const float* x    = (const float*)d_in[0];
  const float* mask = (const float*)d_in[1];
  const float* wq   = (const float*)d_in[2];
  const float* bq   = (const float*)d_in[3];
  const float* wk   = (const float*)d_in[4];
  const float* bk   = (const float*)d_in[5];
  const float* wv   = (const float*)d_in[6];
  const float* bv   = (const float*)d_in[7];
  float* out = (float*)d_out;

  char* ws = (char*)d_ws;
  const size_t MB = 1024 * 1024;
  short* x_bf = (short*)(ws);             // 16 MB [8192,1024]
  short* Vt   = (short*)(ws);             // aliases x_bf (x_bf dead after QKV gemms)
  short* w_bf = (short*)(ws + 16 * MB);   // 6 MB  [3][1024,1024]
  short* Q    = (short*)(ws + 22 * MB);   // 16 MB
  short* Kb   = (short*)(ws + 38 * MB);   // 16 MB
  short* V    = (short*)(ws + 54 * MB);   // 16 MB
  short* P    = (short*)(ws + 70 * MB);   // 32 MB [4][2048][2048] scores then probs

  // casts
  cvt_kernel<<<8192, 256, 0, stream>>>(x, x_bf, 2097152);
  cvt_kernel<<<1024, 256, 0, stream>>>(wq, w_bf, 262144);
  cvt_kernel<<<1024, 256, 0, stream>>>(wk, w_bf + 1048576, 262144);
  cvt_kernel<<<1024, 256, 0, stream>>>(wv, w_bf + 2097152, 262144);

  // QKV projections: [8192,1024] x [1024,1024]^T (+bias) -> bf16
  gemm_bt<0><<<dim3(64, 8, 1), 256, 0, stream>>>(x_bf, w_bf, Q, bq, 1.f,
                                                 8192, 1024, 1024, 0, 0, 0);
  gemm_bt<0><<<dim3(64, 8, 1), 256, 0, stream>>>(x_bf, w_bf + 1048576, Kb, bk, 1.f,
                                                 8192, 1024, 1024, 0, 0, 0);
  gemm_bt<0><<<dim3(64, 8, 1), 256, 0, stream>>>(x_bf, w_bf + 2097152, V, bv, 1.f,
                                                 8192, 1024, 1024, 0, 0, 0);

  transpose_v<<<dim3(64, 32, 4), 256, 0, stream>>>(V, Vt);

  // scores = Q K^T / 32 + mask   (per batch, M=N=2048, K=1024) -> bf16
  gemm_bt<1><<<dim3(16, 16, 4), 256, 0, stream>>>(Q, Kb, P, mask, 0.03125f,
                                                  2048, 2048, 1024,
                                                  2097152, 2097152, 4194304);

  softmax_kernel<<<8192, 256, 0, stream>>>(P);

  // out = P V   (A=P[q,k], B=Vt[d,k], M=2048, N=1024, K=2048) -> fp32
  gemm_bt<2><<<dim3(16, 8, 4), 256, 0, stream>>>(P, Vt, out, nullptr, 1.f,
                                                 2048, 1024, 2048,
                                                 4194304, 2097152, 2097152);
}

// Round 2
// 323.618 us; speedup vs baseline: 1.0918x; 1.0918x over previous
//
#include <hip/hip_runtime.h>

// SimpleSelfAttention: B=4, S=2048, D=1024, fp32 in/out, bf16 MFMA internally.
// R2: global_load_lds width=16 staging (m97 structure) + XOR bank swizzle
//     + batched QKV gemm (z=3).

typedef __attribute__((ext_vector_type(8))) short short8;
typedef __attribute__((ext_vector_type(4))) short short4v;
typedef __attribute__((ext_vector_type(4))) float float4v;

__device__ __forceinline__ short f2bf(float f) {
  unsigned u = __builtin_bit_cast(unsigned, f);
  u += 0x7fffu + ((u >> 16) & 1u);  // RNE; inputs finite
  return (short)(u >> 16);
}
__device__ __forceinline__ float bf2f(short s) {
  unsigned u = ((unsigned)(unsigned short)s) << 16;
  return __builtin_bit_cast(float, u);
}

// async global->LDS, 16B per lane. LDS dest = wave-uniform base + lane*16.
__device__ __forceinline__ void gl2lds16(const void* g, void* l) {
  __builtin_amdgcn_global_load_lds((const __attribute__((address_space(1))) void*)g,
                                   (__attribute__((address_space(3))) void*)l, 16, 0, 0);
}

// ---------- fp32 -> bf16 cast, n4 = n/4 ----------
__global__ __launch_bounds__(256) void cvt_kernel(const float* __restrict__ in,
                                                  short* __restrict__ out, int n4) {
  int i = blockIdx.x * 256 + threadIdx.x;
  if (i < n4) {
    float4v v = ((const float4v*)in)[i];
    short4v o;
    o.x = f2bf(v.x); o.y = f2bf(v.y); o.z = f2bf(v.z); o.w = f2bf(v.w);
    ((short4v*)out)[i] = o;
  }
}

__global__ __launch_bounds__(256) void concat_bias(const float* __restrict__ a,
                                                   const float* __restrict__ b,
                                                   const float* __restrict__ c,
                                                   float* __restrict__ o) {
  int i = blockIdx.x * 256 + threadIdx.x;  // 12 blocks * 256 = 3072
  o[i] = i < 1024 ? a[i] : (i < 2048 ? b[i - 1024] : c[i - 2048]);
}

// ---------- C[m,n] = sum_k A[m,k]*B[n,k] (both K-contiguous), 128x128 tile ----------
// Staging via global_load_lds; chunk (r,c) of each 128x32 tile stored at LDS
// chunk slot r*4 + (c ^ ((r>>1)&3))  (XOR swizzle -> conflict-free ds_read_b128).
// EPI 0: +bias[n] (aux+bz*auxb), store bf16.  EPI 1: *scale + mask[m*N+n], bf16.
// EPI 2: store fp32.
template <int EPI>
__global__ __launch_bounds__(256) void gemm_bt(const short* __restrict__ Aall,
                                               const short* __restrict__ Ball,
                                               void* __restrict__ Call,
                                               const float* __restrict__ aux, float scale,
                                               int M, int N, int Kd,
                                               long ab, long bb, long cb, long auxb) {
  const int bz = blockIdx.z;
  const short* A = Aall + (long)bz * ab;
  const short* Bm = Ball + (long)bz * bb;
  const float* auxp = aux + (long)bz * auxb;

  const int m0 = blockIdx.x * 128;
  const int n0 = blockIdx.y * 128;

  __shared__ alignas(16) short As[128][32];
  __shared__ alignas(16) short Bs[128][32];

  const int t = threadIdx.x;
  const int lane = t & 63, wave = t >> 6;
  const int wm = (wave & 1) * 64, wn = (wave >> 1) * 64;  // wave -> 64x64 subtile
  const int col = lane & 15, quad = lane >> 4;

  // staging: per wave, 2 calls for A + 2 for B; each call covers 16 rows.
  const int r_off = lane >> 2;   // 0..15
  const int cp = lane & 3;       // stored chunk slot within row
  // reader swizzle
  const int rq = (quad ^ ((col >> 1) & 3)) * 8;

  float4v acc[4][4] = {};

  for (int kt = 0; kt < Kd; kt += 32) {
#pragma unroll
    for (int u = 0; u < 2; ++u) {
      const int rowbase = wave * 32 + u * 16;
      const int r = rowbase + r_off;
      const int c = cp ^ ((r >> 1) & 3);  // global chunk that belongs in slot cp
      const long goff = (long)r * Kd + kt + c * 8;
      short* lA = &As[rowbase][0] + lane * 8;
      short* lB = &Bs[rowbase][0] + lane * 8;
      gl2lds16(&A[(long)m0 * Kd + goff], lA);
      gl2lds16(&Bm[(long)n0 * Kd + goff], lB);
    }
    __syncthreads();

    short8 af[4], bfr[4];
#pragma unroll
    for (int i = 0; i < 4; ++i) af[i] = *(const short8*)&As[wm + i * 16 + col][rq];
#pragma unroll
    for (int j = 0; j < 4; ++j) bfr[j] = *(const short8*)&Bs[wn + j * 16 + col][rq];
#pragma unroll
    for (int i = 0; i < 4; ++i)
#pragma unroll
      for (int j = 0; j < 4; ++j)
        acc[i][j] = __builtin_amdgcn_mfma_f32_16x16x32_bf16(af[i], bfr[j], acc[i][j], 0, 0, 0);
    __syncthreads();
  }

  // C/D layout: col = lane&15, row = quad*4 + reg  (m89-verified)
#pragma unroll
  for (int i = 0; i < 4; ++i) {
#pragma unroll
    for (int j = 0; j < 4; ++j) {
      const int n = n0 + wn + j * 16 + col;
      float addv = 0.f;
      if (EPI == 0) addv = auxp[n];
#pragma unroll
      for (int r = 0; r < 4; ++r) {
        const int m = m0 + wm + i * 16 + quad * 4 + r;
        float v = acc[i][j][r];
        if (EPI == 0) {
          ((short*)Call)[(long)bz * cb + (long)m * N + n] = f2bf(v + addv);
        } else if (EPI == 1) {
          v = v * scale + auxp[(long)m * N + n];
          ((short*)Call)[(long)bz * cb + (long)m * N + n] = f2bf(v);
        } else {
          ((float*)Call)[(long)bz * cb + (long)m * N + n] = v;
        }
      }
    }
  }
}

// ---------- V[b][s][d] -> Vt[b][d][s], 32x32 tiles ----------
__global__ __launch_bounds__(256) void transpose_v(const short* __restrict__ V,
                                                   short* __restrict__ Vt) {
  __shared__ short tile[32][33];
  const int b = blockIdx.z;
  const int s0 = blockIdx.x * 32, d0 = blockIdx.y * 32;
  const int tx = threadIdx.x & 31, ty = threadIdx.x >> 5;
  const short* src = V + (long)b * 2048 * 1024;
#pragma unroll
  for (int q = 0; q < 4; ++q) {
    int r = ty + q * 8;
    tile[r][tx] = src[(long)(s0 + r) * 1024 + d0 + tx];
  }
  __syncthreads();
  short* dst = Vt + (long)b * 1024 * 2048;
#pragma unroll
  for (int q = 0; q < 4; ++q) {
    int dr = ty + q * 8;
    dst[(long)(d0 + dr) * 2048 + s0 + tx] = tile[tx][dr];
  }
}

// ---------- softmax over rows of 2048 bf16, in place ----------
__global__ __launch_bounds__(256) void softmax_kernel(short* __restrict__ Sb) {
  const long row = blockIdx.x;
  short* p = Sb + row * 2048;
  const int t = threadIdx.x;
  short8 raw = *(short8*)(p + t * 8);
  float v[8];
#pragma unroll
  for (int e = 0; e < 8; ++e) v[e] = bf2f(raw[e]);

  float mx = v[0];
#pragma unroll
  for (int e = 1; e < 8; ++e) mx = fmaxf(mx, v[e]);
#pragma unroll
  for (int off = 32; off > 0; off >>= 1) mx = fmaxf(mx, __shfl_xor(mx, off));
  __shared__ float redm[4], reds[4];
  if ((t & 63) == 0) redm[t >> 6] = mx;
  __syncthreads();
  mx = fmaxf(fmaxf(redm[0], redm[1]), fmaxf(redm[2], redm[3]));

  float s = 0.f, ev[8];
#pragma unroll
  for (int e = 0; e < 8; ++e) {
    ev[e] = exp2f((v[e] - mx) * 1.4426950408889634f);
    s += ev[e];
  }
#pragma unroll
  for (int off = 32; off > 0; off >>= 1) s += __shfl_xor(s, off);
  if ((t & 63) == 0) reds[t >> 6] = s;
  __syncthreads();
  s = reds[0] + reds[1] + reds[2] + reds[3];
  const float inv = 1.f / s;

  short8 outp;
#pragma unroll
  for (int e = 0; e < 8; ++e) outp[e] = f2bf(ev[e] * inv);
  *(short8*)(p + t * 8) = outp;
}

extern "C" void kernel_launch(void* const* d_in, const int* in_sizes, int n_in,
                              void* d_out, int out_size, void* d_ws, size_t ws_size,
                              hipStream_t stream) {
  const float* x    = (const float*)d_in[0];
  const float* mask = (const float*)d_in[1];
  const float* wq   = (const float*)d_in[2];
  const float* bq   = (const float*)d_in[3];
  const float* wk   = (const float*)d_in[4];
  const float* bk   = (const float*)d_in[5];
  const float* wv   = (const float*)d_in[6];
  const float* bv   = (const float*)d_in[7];
  float* out = (float*)d_out;

  char* ws = (char*)d_ws;
  const size_t MB = 1024 * 1024;
  short* x_bf = (short*)(ws);             // 16 MB [8192,1024]; later aliased by Vt
  short* Vt   = (short*)(ws);             // [4][1024][2048]
  short* w_bf = (short*)(ws + 16 * MB);   // 6 MB [3][1024,1024]
  short* QKV  = (short*)(ws + 22 * MB);   // 48 MB [3][8192,1024]
  short* P    = (short*)(ws + 70 * MB);   // 32 MB [4][2048][2048]
  float* bcat = (float*)(ws + 70 * MB);   // 12 KB, aliases head of P (dead before P written)

  // casts
  cvt_kernel<<<8192, 256, 0, stream>>>(x, x_bf, 2097152);
  cvt_kernel<<<1024, 256, 0, stream>>>(wq, w_bf, 262144);
  cvt_kernel<<<1024, 256, 0, stream>>>(wk, w_bf + 1048576, 262144);
  cvt_kernel<<<1024, 256, 0, stream>>>(wv, w_bf + 2097152, 262144);
  concat_bias<<<12, 256, 0, stream>>>(bq, bk, bv, bcat);

  // QKV projections, batched z=3: [8192,1024] x [1024,1024]^T + bias -> bf16
  gemm_bt<0><<<dim3(64, 8, 3), 256, 0, stream>>>(x_bf, w_bf, QKV, bcat, 1.f,
                                                 8192, 1024, 1024,
                                                 0, 1048576, 8388608, 1024);

  short* Q  = QKV;
  short* Kb = QKV + 8388608;
  short* V  = QKV + 16777216;
  transpose_v<<<dim3(64, 32, 4), 256, 0, stream>>>(V, Vt);

  // scores = Q K^T / 32 + mask   (per batch, M=N=2048, K=1024) -> bf16
  gemm_bt<1><<<dim3(16, 16, 4), 256, 0, stream>>>(Q, Kb, P, mask, 0.03125f,
                                                  2048, 2048, 1024,
                                                  2097152, 2097152, 4194304, 0);

  softmax_kernel<<<8192, 256, 0, stream>>>(P);

  // out = P V   (A=P[q,k], B=Vt[d,k], M=2048, N=1024, K=2048) -> fp32
  gemm_bt<2><<<dim3(16, 8, 4), 256, 0, stream>>>(P, Vt, out, nullptr, 1.f,
                                                 2048, 1024, 2048,
                                                 4194304, 2097152, 2097152, 0);
}

// Round 3
// 284.456 us; speedup vs baseline: 1.2421x; 1.1377x over previous
//
#include <hip/hip_runtime.h>

// SimpleSelfAttention: B=4, S=2048, D=1024, fp32 in/out, bf16 MFMA internally.
// R3: BK=64 K-loop (half the barriers), softmax fused away (scores store
//     unnormalized exp; PV computes row sums via ones-MFMA and divides),
//     merged prep kernel. 6 dispatches total.

typedef __attribute__((ext_vector_type(8))) short short8;
typedef __attribute__((ext_vector_type(4))) short short4v;
typedef __attribute__((ext_vector_type(4))) float float4v;

__device__ __forceinline__ short f2bf(float f) {
  unsigned u = __builtin_bit_cast(unsigned, f);
  u += 0x7fffu + ((u >> 16) & 1u);  // RNE; inputs finite
  return (short)(u >> 16);
}

// async global->LDS, 16B per lane. LDS dest = wave-uniform base + lane*16.
__device__ __forceinline__ void gl2lds16(const void* g, void* l) {
  __builtin_amdgcn_global_load_lds((const __attribute__((address_space(1))) void*)g,
                                   (__attribute__((address_space(3))) void*)l, 16, 0, 0);
}

// ---------- fp32 -> bf16 cast, n4 = n/4 ----------
__global__ __launch_bounds__(256) void cvt_kernel(const float* __restrict__ in,
                                                  short* __restrict__ out, int n4) {
  int i = blockIdx.x * 256 + threadIdx.x;
  if (i < n4) {
    float4v v = ((const float4v*)in)[i];
    short4v o;
    o.x = f2bf(v.x); o.y = f2bf(v.y); o.z = f2bf(v.z); o.w = f2bf(v.w);
    ((short4v*)out)[i] = o;
  }
}

// ---------- weights cvt (3x [1024,1024]) + bias concat, one dispatch ----------
__global__ __launch_bounds__(256) void prep_kernel(const float* __restrict__ wq,
                                                   const float* __restrict__ wk,
                                                   const float* __restrict__ wv,
                                                   const float* __restrict__ bq,
                                                   const float* __restrict__ bk,
                                                   const float* __restrict__ bv,
                                                   short* __restrict__ w_bf,
                                                   float* __restrict__ bcat) {
  int b = blockIdx.x;
  if (b < 3072) {
    int seg = b >> 10;  // 0,1,2 (wave-uniform)
    const float* w = seg == 0 ? wq : (seg == 1 ? wk : wv);
    int i = (b - (seg << 10)) * 256 + threadIdx.x;  // 0..262143 float4s
    float4v v = ((const float4v*)w)[i];
    short4v o;
    o.x = f2bf(v.x); o.y = f2bf(v.y); o.z = f2bf(v.z); o.w = f2bf(v.w);
    ((short4v*)(w_bf + (long)seg * 1048576))[i] = o;
  } else {
    int i = (b - 3072) * 256 + threadIdx.x;
    if (i < 3072) bcat[i] = i < 1024 ? bq[i] : (i < 2048 ? bk[i - 1024] : bv[i - 2048]);
  }
}

// ---------- C[m,n] = sum_k A[m,k]*B[n,k] (both K-contiguous), 128x128 tile, BK=64 ----
// LDS: chunk (16B) c of row r stored at slot c ^ (r&7). Readers (16-lane phases)
// hit 8 distinct 4-bank groups x 2 lanes each -> conflict-free (m136: 2-way free).
// EPI 0: +bias[n] (aux+bz*auxb), store bf16.
// EPI 1: store bf16 exp(v*scale + mask[m*N+n])   (unnormalized softmax numerator)
// EPI 2: row sums via ones-MFMA; store fp32 acc/rowsum.
template <int EPI>
__global__ __launch_bounds__(256) void gemm_bt(const short* __restrict__ Aall,
                                               const short* __restrict__ Ball,
                                               void* __restrict__ Call,
                                               const float* __restrict__ aux, float scale,
                                               int M, int N, int Kd,
                                               long ab, long bb, long cb, long auxb) {
  const int bz = blockIdx.z;
  const short* A = Aall + (long)bz * ab;
  const short* Bm = Ball + (long)bz * bb;
  const float* auxp = aux + (long)bz * auxb;

  const int m0 = blockIdx.x * 128;
  const int n0 = blockIdx.y * 128;

  __shared__ alignas(16) short As[128][64];
  __shared__ alignas(16) short Bs[128][64];

  const int t = threadIdx.x;
  const int lane = t & 63, wave = t >> 6;
  const int wm = (wave & 1) * 64, wn = (wave >> 1) * 64;  // wave -> 64x64 subtile
  const int col = lane & 15, quad = lane >> 4;

  // staging: per wave, 4 calls for A + 4 for B; each call = 8 rows x 128B.
  const int r_loc = lane >> 3;  // 0..7
  const int slot = lane & 7;
  const int cch = slot ^ r_loc;  // global chunk that belongs in this slot
  // reader swizzle constant
  const int sw = col & 7;

  float4v acc[4][4] = {};
  float4v lacc[4] = {};  // EPI2 row sums
  short8 ones;
  if (EPI == 2) {
#pragma unroll
    for (int e = 0; e < 8; ++e) ones[e] = (short)0x3F80;  // bf16 1.0
  }

  for (int kt = 0; kt < Kd; kt += 64) {
#pragma unroll
    for (int u = 0; u < 4; ++u) {
      const int rowbase = wave * 32 + u * 8;
      const int r = rowbase + r_loc;
      const long goff = (long)r * Kd + kt + cch * 8;
      short* lA = &As[rowbase][0] + lane * 8;
      short* lB = &Bs[rowbase][0] + lane * 8;
      gl2lds16(&A[(long)m0 * Kd + goff], lA);
      gl2lds16(&Bm[(long)n0 * Kd + goff], lB);
    }
    __syncthreads();

#pragma unroll
    for (int s = 0; s < 2; ++s) {
      short8 af[4], bfr[4];
#pragma unroll
      for (int i = 0; i < 4; ++i)
        af[i] = *(const short8*)&As[wm + i * 16 + col][((s * 4 + quad) ^ sw) * 8];
#pragma unroll
      for (int j = 0; j < 4; ++j)
        bfr[j] = *(const short8*)&Bs[wn + j * 16 + col][((s * 4 + quad) ^ sw) * 8];
#pragma unroll
      for (int i = 0; i < 4; ++i) {
#pragma unroll
        for (int j = 0; j < 4; ++j)
          acc[i][j] = __builtin_amdgcn_mfma_f32_16x16x32_bf16(af[i], bfr[j], acc[i][j], 0, 0, 0);
        if (EPI == 2)
          lacc[i] = __builtin_amdgcn_mfma_f32_16x16x32_bf16(af[i], ones, lacc[i], 0, 0, 0);
      }
    }
    __syncthreads();
  }

  // C/D layout: col = lane&15, row = quad*4 + reg  (m89-verified)
  const float LOG2E = 1.44269504f;
  const float c1 = scale * LOG2E;
#pragma unroll
  for (int i = 0; i < 4; ++i) {
    float4v inv;
    if (EPI == 2) {
#pragma unroll
      for (int r = 0; r < 4; ++r) inv[r] = 1.f / lacc[i][r];
    }
#pragma unroll
    for (int j = 0; j < 4; ++j) {
      const int n = n0 + wn + j * 16 + col;
      float addv = 0.f;
      if (EPI == 0) addv = auxp[n];
#pragma unroll
      for (int r = 0; r < 4; ++r) {
        const int m = m0 + wm + i * 16 + quad * 4 + r;
        float v = acc[i][j][r];
        if (EPI == 0) {
          ((short*)Call)[(long)bz * cb + (long)m * N + n] = f2bf(v + addv);
        } else if (EPI == 1) {
          float mv = auxp[(long)m * N + n];
          float e = exp2f(fmaf(v, c1, mv * LOG2E));  // exp(v*scale+mask), no max: |s|~3
          ((short*)Call)[(long)bz * cb + (long)m * N + n] = f2bf(e);
        } else {
          ((float*)Call)[(long)bz * cb + (long)m * N + n] = v * inv[r];
        }
      }
    }
  }
}

// ---------- V[b][s][d] -> Vt[b][d][s], 32x32 tiles ----------
__global__ __launch_bounds__(256) void transpose_v(const short* __restrict__ V,
                                                   short* __restrict__ Vt) {
  __shared__ short tile[32][33];
  const int b = blockIdx.z;
  const int s0 = blockIdx.x * 32, d0 = blockIdx.y * 32;
  const int tx = threadIdx.x & 31, ty = threadIdx.x >> 5;
  const short* src = V + (long)b * 2048 * 1024;
#pragma unroll
  for (int q = 0; q < 4; ++q) {
    int r = ty + q * 8;
    tile[r][tx] = src[(long)(s0 + r) * 1024 + d0 + tx];
  }
  __syncthreads();
  short* dst = Vt + (long)b * 1024 * 2048;
#pragma unroll
  for (int q = 0; q < 4; ++q) {
    int dr = ty + q * 8;
    dst[(long)(d0 + dr) * 2048 + s0 + tx] = tile[tx][dr];
  }
}

extern "C" void kernel_launch(void* const* d_in, const int* in_sizes, int n_in,
                              void* d_out, int out_size, void* d_ws, size_t ws_size,
                              hipStream_t stream) {
  const float* x    = (const float*)d_in[0];
  const float* mask = (const float*)d_in[1];
  const float* wq   = (const float*)d_in[2];
  const float* bq   = (const float*)d_in[3];
  const float* wk   = (const float*)d_in[4];
  const float* bk   = (const float*)d_in[5];
  const float* wv   = (const float*)d_in[6];
  const float* bv   = (const float*)d_in[7];
  float* out = (float*)d_out;

  char* ws = (char*)d_ws;
  const size_t MB = 1024 * 1024;
  short* x_bf = (short*)(ws);             // 16 MB [8192,1024]; later aliased by Vt
  short* Vt   = (short*)(ws);             // [4][1024][2048]
  short* w_bf = (short*)(ws + 16 * MB);   // 6 MB [3][1024,1024]
  short* QKV  = (short*)(ws + 22 * MB);   // 48 MB [3][8192,1024]
  short* P    = (short*)(ws + 70 * MB);   // 32 MB [4][2048][2048] (unnormalized exp)
  float* bcat = (float*)(ws + 70 * MB);   // 12 KB, aliases head of P (dead before P written)

  prep_kernel<<<3084, 256, 0, stream>>>(wq, wk, wv, bq, bk, bv, w_bf, bcat);
  cvt_kernel<<<8192, 256, 0, stream>>>(x, x_bf, 2097152);

  // QKV projections, batched z=3: [8192,1024] x [1024,1024]^T + bias -> bf16
  gemm_bt<0><<<dim3(64, 8, 3), 256, 0, stream>>>(x_bf, w_bf, QKV, bcat, 1.f,
                                                 8192, 1024, 1024,
                                                 0, 1048576, 8388608, 1024);

  short* Q  = QKV;
  short* Kb = QKV + 8388608;
  short* V  = QKV + 16777216;
  transpose_v<<<dim3(64, 32, 4), 256, 0, stream>>>(V, Vt);

  // P = exp(Q K^T / 32 + mask)   (per batch, M=N=2048, K=1024) -> bf16, unnormalized
  gemm_bt<1><<<dim3(16, 16, 4), 256, 0, stream>>>(Q, Kb, P, mask, 0.03125f,
                                                  2048, 2048, 1024,
                                                  2097152, 2097152, 4194304, 0);

  // out = (P V) / rowsum(P)   (A=P[q,k], B=Vt[d,k], M=2048, N=1024, K=2048) -> fp32
  gemm_bt<2><<<dim3(16, 8, 4), 256, 0, stream>>>(P, Vt, out, nullptr, 1.f,
                                                 2048, 1024, 2048,
                                                 4194304, 2097152, 2097152, 0);
}

// Round 4
// 277.928 us; speedup vs baseline: 1.2713x; 1.0235x over previous
//
#include <hip/hip_runtime.h>

// SimpleSelfAttention: B=4, S=2048, D=1024, fp32 in/out, bf16 MFMA internally.
// R4: 32x32x16 MFMA (21% more FLOP/cyc, half the MFMA issue slots),
//     transpose_v replaced by a Vt GEMM (Vt = W_v x^T + bv), rowsum kernel
//     instead of ones-MFMA in PV. 7 dispatches.

typedef __attribute__((ext_vector_type(8))) short short8;
typedef __attribute__((ext_vector_type(4))) short short4v;
typedef __attribute__((ext_vector_type(4))) float float4v;
typedef __attribute__((ext_vector_type(16))) float float16v;

__device__ __forceinline__ short f2bf(float f) {
  unsigned u = __builtin_bit_cast(unsigned, f);
  u += 0x7fffu + ((u >> 16) & 1u);  // RNE; inputs finite
  return (short)(u >> 16);
}
__device__ __forceinline__ float bf2f(short s) {
  unsigned u = ((unsigned)(unsigned short)s) << 16;
  return __builtin_bit_cast(float, u);
}

// async global->LDS, 16B per lane. LDS dest = wave-uniform base + lane*16.
__device__ __forceinline__ void gl2lds16(const void* g, void* l) {
  __builtin_amdgcn_global_load_lds((const __attribute__((address_space(1))) void*)g,
                                   (__attribute__((address_space(3))) void*)l, 16, 0, 0);
}

// ---------- fp32 -> bf16 cast, n4 = n/4 ----------
__global__ __launch_bounds__(256) void cvt_kernel(const float* __restrict__ in,
                                                  short* __restrict__ out, int n4) {
  int i = blockIdx.x * 256 + threadIdx.x;
  if (i < n4) {
    float4v v = ((const float4v*)in)[i];
    short4v o;
    o.x = f2bf(v.x); o.y = f2bf(v.y); o.z = f2bf(v.z); o.w = f2bf(v.w);
    ((short4v*)out)[i] = o;
  }
}

// ---------- weights cvt (3x [1024,1024]) + bias concat, one dispatch ----------
__global__ __launch_bounds__(256) void prep_kernel(const float* __restrict__ wq,
                                                   const float* __restrict__ wk,
                                                   const float* __restrict__ wv,
                                                   const float* __restrict__ bq,
                                                   const float* __restrict__ bk,
                                                   short* __restrict__ w_bf,
                                                   float* __restrict__ bcat) {
  int b = blockIdx.x;
  if (b < 3072) {
    int seg = b >> 10;  // 0,1,2 (wave-uniform)
    const float* w = seg == 0 ? wq : (seg == 1 ? wk : wv);
    int i = (b - (seg << 10)) * 256 + threadIdx.x;  // 0..262143 float4s
    float4v v = ((const float4v*)w)[i];
    short4v o;
    o.x = f2bf(v.x); o.y = f2bf(v.y); o.z = f2bf(v.z); o.w = f2bf(v.w);
    ((short4v*)(w_bf + (long)seg * 1048576))[i] = o;
  } else {
    int i = (b - 3072) * 256 + threadIdx.x;  // Q,K biases only (bv used by Vt gemm)
    if (i < 2048) bcat[i] = i < 1024 ? bq[i] : bk[i - 1024];
  }
}

// ---------- C[m,n] = sum_k A[m,k]*B[n,k], 128x128 tile, BK=64, 32x32x16 MFMA ----
// A row stride = Kd; B row stride = Bld; C row stride = N.
// LDS: 16B chunk c of row r stored at slot c ^ (r&7) -> 2-way (free) ds_read_b128.
// EPI 0: +bias[n] (aux+bz*auxb), store bf16.
// EPI 1: store bf16 exp(v*scale + mask[m*N+n])   (unnormalized softmax numerator)
// EPI 2: store fp32 v / rs[m]  (rs = aux+bz*auxb)
// EPI 3: +bias[m] (aux), store bf16.
template <int EPI>
__global__ __launch_bounds__(256) void gemm_bt(const short* __restrict__ Aall,
                                               const short* __restrict__ Ball,
                                               void* __restrict__ Call,
                                               const float* __restrict__ aux, float scale,
                                               int M, int N, int Kd, int Bld,
                                               long ab, long bb, long cb, long auxb) {
  const int bz = blockIdx.z;
  const short* A = Aall + (long)bz * ab;
  const short* Bm = Ball + (long)bz * bb;
  const float* auxp = aux + (long)bz * auxb;

  const int m0 = blockIdx.x * 128;
  const int n0 = blockIdx.y * 128;

  __shared__ alignas(16) short As[128][64];
  __shared__ alignas(16) short Bs[128][64];

  const int t = threadIdx.x;
  const int lane = t & 63, wave = t >> 6;
  const int wm = (wave & 1) * 64, wn = (wave >> 1) * 64;  // wave -> 64x64 subtile
  const int col32 = lane & 31, half = lane >> 5;

  // staging: per wave, 4 calls for A + 4 for B; each call = 8 rows x 128B.
  const int r_loc = lane >> 3;   // 0..7
  const int slot = lane & 7;
  const int cch = slot ^ r_loc;  // global chunk that belongs in this slot
  const int sw = col32 & 7;      // reader swizzle

  float16v acc[2][2] = {};

  for (int kt = 0; kt < Kd; kt += 64) {
#pragma unroll
    for (int u = 0; u < 4; ++u) {
      const int rowbase = wave * 32 + u * 8;
      const int r = rowbase + r_loc;
      gl2lds16(&A[(long)(m0 + r) * Kd + kt + cch * 8], &As[rowbase][0] + lane * 8);
      gl2lds16(&Bm[(long)(n0 + r) * Bld + kt + cch * 8], &Bs[rowbase][0] + lane * 8);
    }
    __syncthreads();

#pragma unroll
    for (int s = 0; s < 4; ++s) {  // 4 k-steps of 16
      const int c = s * 2 + half;  // chunk holding this lane's 8 k-elements
      short8 af[2], bfr[2];
#pragma unroll
      for (int i = 0; i < 2; ++i)
        af[i] = *(const short8*)&As[wm + i * 32 + col32][(c ^ sw) * 8];
#pragma unroll
      for (int j = 0; j < 2; ++j)
        bfr[j] = *(const short8*)&Bs[wn + j * 32 + col32][(c ^ sw) * 8];
#pragma unroll
      for (int i = 0; i < 2; ++i)
#pragma unroll
        for (int j = 0; j < 2; ++j)
          acc[i][j] = __builtin_amdgcn_mfma_f32_32x32x16_bf16(af[i], bfr[j], acc[i][j], 0, 0, 0);
    }
    __syncthreads();
  }

  // C/D layout (m74/m101): col = lane&31, row = (reg&3) + 8*(reg>>2) + 4*half
  const float LOG2E = 1.44269504f;
  const float c1 = scale * LOG2E;
#pragma unroll
  for (int i = 0; i < 2; ++i) {
    float invv[16], addm[16];
    if (EPI == 2) {
#pragma unroll
      for (int r = 0; r < 16; ++r) {
        const int m = m0 + wm + i * 32 + (r & 3) + 8 * (r >> 2) + 4 * half;
        invv[r] = __builtin_amdgcn_rcpf(auxp[m]);
      }
    }
    if (EPI == 3) {
#pragma unroll
      for (int r = 0; r < 16; ++r) {
        const int m = m0 + wm + i * 32 + (r & 3) + 8 * (r >> 2) + 4 * half;
        addm[r] = auxp[m];
      }
    }
#pragma unroll
    for (int j = 0; j < 2; ++j) {
      const int n = n0 + wn + j * 32 + col32;
      float addn = 0.f;
      if (EPI == 0) addn = auxp[n];
#pragma unroll
      for (int r = 0; r < 16; ++r) {
        const int m = m0 + wm + i * 32 + (r & 3) + 8 * (r >> 2) + 4 * half;
        float v = acc[i][j][r];
        if (EPI == 0) {
          ((short*)Call)[(long)bz * cb + (long)m * N + n] = f2bf(v + addn);
        } else if (EPI == 1) {
          float mv = auxp[(long)m * N + n];
          float e = exp2f(fmaf(v, c1, mv * LOG2E));  // exp(v*scale+mask); |s|~3, safe
          ((short*)Call)[(long)bz * cb + (long)m * N + n] = f2bf(e);
        } else if (EPI == 2) {
          ((float*)Call)[(long)bz * cb + (long)m * N + n] = v * invv[r];
        } else {
          ((short*)Call)[(long)bz * cb + (long)m * N + n] = f2bf(v + addm[r]);
        }
      }
    }
  }
}

// ---------- rowsum of P: rs[row] = sum_k P[row][k], rows of 2048 bf16 ----------
__global__ __launch_bounds__(256) void rowsum_kernel(const short* __restrict__ P,
                                                     float* __restrict__ rs) {
  const long row = blockIdx.x;
  const int t = threadIdx.x;
  short8 raw = *(const short8*)(P + row * 2048 + t * 8);
  float s = 0.f;
#pragma unroll
  for (int e = 0; e < 8; ++e) s += bf2f(raw[e]);
#pragma unroll
  for (int off = 32; off > 0; off >>= 1) s += __shfl_xor(s, off);
  __shared__ float red[4];
  if ((t & 63) == 0) red[t >> 6] = s;
  __syncthreads();
  if (t == 0) rs[row] = red[0] + red[1] + red[2] + red[3];
}

extern "C" void kernel_launch(void* const* d_in, const int* in_sizes, int n_in,
                              void* d_out, int out_size, void* d_ws, size_t ws_size,
                              hipStream_t stream) {
  const float* x    = (const float*)d_in[0];
  const float* mask = (const float*)d_in[1];
  const float* wq   = (const float*)d_in[2];
  const float* bq   = (const float*)d_in[3];
  const float* wk   = (const float*)d_in[4];
  const float* bk   = (const float*)d_in[5];
  const float* wv   = (const float*)d_in[6];
  const float* bv   = (const float*)d_in[7];
  float* out = (float*)d_out;

  char* ws = (char*)d_ws;
  const size_t MB = 1024 * 1024;
  short* x_bf = (short*)(ws);             // 16 MB [8192,1024]
  short* w_bf = (short*)(ws + 16 * MB);   // 6 MB [3][1024,1024]
  float* rs   = (float*)(ws + 16 * MB);   // 32 KB [4][2048], aliases w_bf (dead by then)
  short* QK   = (short*)(ws + 22 * MB);   // 32 MB [2][8192,1024]
  short* Vt   = (short*)(ws + 54 * MB);   // 16 MB [1024][8192] = [d][b*2048+s]
  short* P    = (short*)(ws + 70 * MB);   // 32 MB [4][2048][2048] (unnormalized exp)
  float* bcat = (float*)(ws + 70 * MB);   // 8 KB, aliases head of P (dead before P written)

  prep_kernel<<<3080, 256, 0, stream>>>(wq, wk, wv, bq, bk, w_bf, bcat);
  cvt_kernel<<<8192, 256, 0, stream>>>(x, x_bf, 2097152);

  // Q,K projections, batched z=2: [8192,1024] x [1024,1024]^T + bias -> bf16
  gemm_bt<0><<<dim3(64, 8, 2), 256, 0, stream>>>(x_bf, w_bf, QK, bcat, 1.f,
                                                 8192, 1024, 1024, 1024,
                                                 0, 1048576, 8388608, 1024);

  // Vt[d][sg] = sum_k w_v[d,k] x[sg,k] + bv[d]  (M=1024, N=8192, bias on rows)
  gemm_bt<3><<<dim3(8, 64, 1), 256, 0, stream>>>(w_bf + 2097152, x_bf, Vt, bv, 1.f,
                                                 1024, 8192, 1024, 1024,
                                                 0, 0, 0, 0);

  short* Q  = QK;
  short* Kb = QK + 8388608;

  // P = exp(Q K^T / 32 + mask)   (per batch, M=N=2048, K=1024) -> bf16, unnormalized
  gemm_bt<1><<<dim3(16, 16, 4), 256, 0, stream>>>(Q, Kb, P, mask, 0.03125f,
                                                  2048, 2048, 1024, 1024,
                                                  2097152, 2097152, 4194304, 0);

  rowsum_kernel<<<8192, 256, 0, stream>>>(P, rs);

  // out = (P V) / rs   (A=P[q,k], B=Vt rows at bz*2048, M=2048, N=1024, K=2048)
  gemm_bt<2><<<dim3(16, 8, 4), 256, 0, stream>>>(P, Vt, out, rs, 1.f,
                                                 2048, 1024, 2048, 8192,
                                                 4194304, 2048, 2097152, 2048);
}